// Round 3
// baseline (109.611 us; speedup 1.0000x reference)
//
#include <hip/hip_runtime.h>
#include <hip/hip_bf16.h>

// Attention cosine-sim + mask + softmax — two-kernel split.
// query (16,16,1,128) f32, key (16,16,4096,128) f32, mask (16,4096) i32
// out (16,16,4096) f32
//
// K1: pure streaming score kernel, 8 blocks/CU for max read BW, writes raw
//     scores into d_out.
// K2: per-(b,h) in-place mask + softmax on d_out (16 KB/block, L3-resident).

constexpr int Bdim = 16, Hdim = 16, Ldim = 4096, Ddim = 128;
constexpr float EPSF = 1e-8f;
constexpr float NEGF = -1000000000.0f;

// 32-lane-group sum via DPP row ops (VALU pipe, zero DS traffic).
// Valid result in lane 31 of each 32-lane half (lanes 31 and 63 of the wave).
__device__ __forceinline__ float dpp_sum32(float v) {
    v += __int_as_float(__builtin_amdgcn_update_dpp(0, __float_as_int(v), 0x111, 0xf, 0xf, true)); // row_shr:1
    v += __int_as_float(__builtin_amdgcn_update_dpp(0, __float_as_int(v), 0x112, 0xf, 0xf, true)); // row_shr:2
    v += __int_as_float(__builtin_amdgcn_update_dpp(0, __float_as_int(v), 0x114, 0xf, 0xf, true)); // row_shr:4
    v += __int_as_float(__builtin_amdgcn_update_dpp(0, __float_as_int(v), 0x118, 0xf, 0xf, true)); // row_shr:8
    v += __int_as_float(__builtin_amdgcn_update_dpp(0, __float_as_int(v), 0x142, 0xa, 0xf, true)); // row_bcast:15 -> rows 1,3
    return v;
}

// ---------------- K1: scores ----------------
// grid = 256 bh * 8 chunks = 2048 blocks, 256 threads (8 groups of 32).
// Each block covers 512 consecutive key rows of one (b,h).
constexpr int K1_THREADS = 256;
constexpr int K1_CHUNKS  = 8;                    // chunks per (b,h)
constexpr int K1_ROWS    = Ldim / K1_CHUNKS;     // 512 rows per block
constexpr int K1_UNROLL  = 4;
constexpr int K1_GROUPS  = K1_THREADS / 32;      // 8
constexpr int K1_RPI     = K1_GROUPS * K1_UNROLL; // 32 rows per iteration

__global__ __launch_bounds__(K1_THREADS, 8) void attn_scores(
    const float* __restrict__ q,
    const float* __restrict__ k,
    float* __restrict__ scores)
{
    const int bid   = blockIdx.x;
    const int bh    = bid >> 3;                  // / K1_CHUNKS
    const int chunk = bid & (K1_CHUNKS - 1);
    const int rowbase = chunk * K1_ROWS;

    const float4* qrow  = reinterpret_cast<const float4*>(q + (size_t)bh * Ddim);
    const float4* krow  = reinterpret_cast<const float4*>(k + (size_t)bh * Ldim * Ddim);
    float*        srow  = scores + (size_t)bh * Ldim;

    const int tid  = threadIdx.x;
    const int g    = tid >> 5;                   // group 0..7
    const int lane = tid & 31;
    const bool writer = (lane == 31);

    float4 qv = qrow[lane];
    float q2 = qv.x*qv.x + qv.y*qv.y + qv.z*qv.z + qv.w*qv.w;
    q2 = dpp_sum32(q2);                          // valid on writer lane
    const float qn = sqrtf(q2);

    #pragma unroll 1
    for (int iter = 0; iter < K1_ROWS / K1_RPI; ++iter) {
        const int r0 = rowbase + iter * K1_RPI + g;   // group's first row this iter
        float4 kv[K1_UNROLL];
        #pragma unroll
        for (int j = 0; j < K1_UNROLL; ++j) {
            kv[j] = krow[(size_t)(r0 + j * K1_GROUPS) * (Ddim / 4) + lane];
        }
        #pragma unroll
        for (int j = 0; j < K1_UNROLL; ++j) {
            float dp = kv[j].x*qv.x + kv[j].y*qv.y + kv[j].z*qv.z + kv[j].w*qv.w;
            float k2 = kv[j].x*kv[j].x + kv[j].y*kv[j].y + kv[j].z*kv[j].z + kv[j].w*kv[j].w;
            dp = dpp_sum32(dp);
            k2 = dpp_sum32(k2);
            if (writer) {
                float denom = fmaxf(qn * sqrtf(k2), EPSF);
                srow[r0 + j * K1_GROUPS] = dp / denom;
            }
        }
    }
}

// ---------------- K2: mask + softmax, in place ----------------
// 256 blocks (one per bh) x 256 threads; 16 elements per thread.
constexpr int K2_THREADS = 256;

__global__ __launch_bounds__(K2_THREADS) void attn_softmax(
    float* __restrict__ io,
    const int* __restrict__ mask)
{
    const int bh = blockIdx.x;
    const int b  = bh >> 4;
    float4*       srow = reinterpret_cast<float4*>(io + (size_t)bh * Ldim);
    const int4*   mrow = reinterpret_cast<const int4*>(mask + (size_t)b * Ldim);

    const int tid = threadIdx.x;
    __shared__ float s_red[4];

    float4 sv[4];
    float lmax = -3.0e9f;   // below NEG so an all-masked row matches reference
    #pragma unroll
    for (int i = 0; i < 4; ++i) {
        const int idx = tid + i * K2_THREADS;
        float4 s = srow[idx];
        int4   m = mrow[idx];
        s.x = (m.x == 0) ? NEGF : s.x;
        s.y = (m.y == 0) ? NEGF : s.y;
        s.z = (m.z == 0) ? NEGF : s.z;
        s.w = (m.w == 0) ? NEGF : s.w;
        sv[i] = s;
        lmax = fmaxf(lmax, fmaxf(fmaxf(s.x, s.y), fmaxf(s.z, s.w)));
    }
    #pragma unroll
    for (int m = 32; m >= 1; m >>= 1) lmax = fmaxf(lmax, __shfl_xor(lmax, m));
    if ((tid & 63) == 0) s_red[tid >> 6] = lmax;
    __syncthreads();
    const float gmax = fmaxf(fmaxf(s_red[0], s_red[1]), fmaxf(s_red[2], s_red[3]));
    __syncthreads();

    float lsum = 0.0f;
    #pragma unroll
    for (int i = 0; i < 4; ++i) {
        sv[i].x = __expf(sv[i].x - gmax);
        sv[i].y = __expf(sv[i].y - gmax);
        sv[i].z = __expf(sv[i].z - gmax);
        sv[i].w = __expf(sv[i].w - gmax);
        lsum += (sv[i].x + sv[i].y) + (sv[i].z + sv[i].w);
    }
    #pragma unroll
    for (int m = 32; m >= 1; m >>= 1) lsum += __shfl_xor(lsum, m);
    if ((tid & 63) == 0) s_red[tid >> 6] = lsum;
    __syncthreads();
    const float gsum = (s_red[0] + s_red[1]) + (s_red[2] + s_red[3]);
    const float rinv = 1.0f / gsum;

    #pragma unroll
    for (int i = 0; i < 4; ++i) {
        float4 s = sv[i];
        s.x *= rinv; s.y *= rinv; s.z *= rinv; s.w *= rinv;
        srow[tid + i * K2_THREADS] = s;
    }
}

extern "C" void kernel_launch(void* const* d_in, const int* in_sizes, int n_in,
                              void* d_out, int out_size, void* d_ws, size_t ws_size,
                              hipStream_t stream) {
    const float* q    = (const float*)d_in[0];
    const float* k    = (const float*)d_in[1];
    const int*   mask = (const int*)d_in[2];
    float*       out  = (float*)d_out;

    attn_scores<<<dim3(Bdim * Hdim * K1_CHUNKS), dim3(K1_THREADS), 0, stream>>>(q, k, out);
    attn_softmax<<<dim3(Bdim * Hdim), dim3(K2_THREADS), 0, stream>>>(out, mask);
}

// Round 5
// 97.792 us; speedup vs baseline: 1.1209x; 1.1209x over previous
//
#include <hip/hip_runtime.h>
#include <hip/hip_bf16.h>

// Attention cosine-sim + mask + softmax — fused, 2 blocks/CU for tail overlap.
// query (16,16,1,128) f32, key (16,16,4096,128) f32, mask (16,4096) i32
// out (16,16,4096) f32

constexpr int Bdim = 16, Hdim = 16, Ldim = 4096, Ddim = 128;
constexpr int NTHREADS = 1024;           // 16 waves
constexpr float EPSF = 1e-8f;
constexpr float NEGF = -1000000000.0f;

// 32-lane-group sum via DPP row ops (VALU pipe, zero DS traffic).
// Valid result in lane 31 of each 32-lane half (lanes 31 and 63 of the wave).
__device__ __forceinline__ float dpp_sum32(float v) {
    v += __int_as_float(__builtin_amdgcn_update_dpp(0, __float_as_int(v), 0x111, 0xf, 0xf, true)); // row_shr:1
    v += __int_as_float(__builtin_amdgcn_update_dpp(0, __float_as_int(v), 0x112, 0xf, 0xf, true)); // row_shr:2
    v += __int_as_float(__builtin_amdgcn_update_dpp(0, __float_as_int(v), 0x114, 0xf, 0xf, true)); // row_shr:4
    v += __int_as_float(__builtin_amdgcn_update_dpp(0, __float_as_int(v), 0x118, 0xf, 0xf, true)); // row_shr:8
    v += __int_as_float(__builtin_amdgcn_update_dpp(0, __float_as_int(v), 0x142, 0xa, 0xf, true)); // row_bcast:15 -> rows 1,3
    return v;
}

// __launch_bounds__(1024, 8): 8 waves/SIMD -> VGPR <= 64 -> 2 blocks/CU, so one
// block's softmax tail overlaps the other block's key streaming.
__global__ __launch_bounds__(NTHREADS, 8) void attn_cos_softmax(
    const float* __restrict__ q,
    const float* __restrict__ k,
    const int* __restrict__ mask,
    float* __restrict__ out)
{
    const int bh = blockIdx.x;           // 0..255
    const int b  = bh >> 4;              // / Hdim
    const float4* qrow = reinterpret_cast<const float4*>(q + (size_t)bh * Ddim);
    const float4* krow = reinterpret_cast<const float4*>(k + (size_t)bh * Ldim * Ddim);
    const int*    mrow = mask + (size_t)b * Ldim;
    float*        orow = out  + (size_t)bh * Ldim;

    __shared__ float s_scores[Ldim];     // 16 KB
    __shared__ float s_red[16];

    const int tid  = threadIdx.x;
    const int g    = tid >> 5;           // 32-lane group id, 0..31
    const int lane = tid & 31;
    const bool writer = (lane == 31);    // DPP reduction lands in lane 31 of each group

    // q fragment (float4 per lane covers the 128-elem row across 32 lanes) + ||q||
    float4 qv = qrow[lane];
    float q2 = qv.x*qv.x + qv.y*qv.y + qv.z*qv.z + qv.w*qv.w;
    q2 = dpp_sum32(q2);                  // valid on writer lane only — that's all we need
    const float qn = sqrtf(q2);

    // ---- score phase: each 32-lane group does one row per sub-step, 8 rows batched ----
    constexpr int UNROLL = 8;
    constexpr int ROWS_PER_ITER = 32 * UNROLL;   // 256 rows per block iteration
    #pragma unroll 1
    for (int iter = 0; iter < Ldim / ROWS_PER_ITER; ++iter) {
        const int base = iter * ROWS_PER_ITER + g;
        float4 kv[UNROLL];
        #pragma unroll
        for (int j = 0; j < UNROLL; ++j) {
            kv[j] = krow[(base + j * 32) * (Ddim / 4) + lane];
        }
        #pragma unroll
        for (int j = 0; j < UNROLL; ++j) {
            float dp = kv[j].x*qv.x + kv[j].y*qv.y + kv[j].z*qv.z + kv[j].w*qv.w;
            float k2 = kv[j].x*kv[j].x + kv[j].y*kv[j].y + kv[j].z*kv[j].z + kv[j].w*kv[j].w;
            dp = dpp_sum32(dp);
            k2 = dpp_sum32(k2);
            if (writer) {
                float denom = fmaxf(qn * sqrtf(k2), EPSF);
                s_scores[base + j * 32] = dp / denom;
            }
        }
    }
    __syncthreads();

    // ---- softmax over L = 4096 (4 elements per thread, in registers) ----
    float sv[4];
    float lmax = -3.0e9f;   // below NEG so an all-masked row matches reference
    #pragma unroll
    for (int i = 0; i < 4; ++i) {
        const int idx = tid + i * NTHREADS;
        float s = s_scores[idx];
        s = (mrow[idx] == 0) ? NEGF : s;
        sv[i] = s;
        lmax = fmaxf(lmax, s);
    }
    #pragma unroll
    for (int m = 32; m >= 1; m >>= 1) lmax = fmaxf(lmax, __shfl_xor(lmax, m));
    if ((tid & 63) == 0) s_red[tid >> 6] = lmax;
    __syncthreads();
    float gmax = s_red[0];
    #pragma unroll
    for (int i = 1; i < 16; ++i) gmax = fmaxf(gmax, s_red[i]);
    __syncthreads();

    float lsum = 0.0f;
    #pragma unroll
    for (int i = 0; i < 4; ++i) {
        sv[i] = __expf(sv[i] - gmax);    // reuse sv as exp values (saves 4 VGPRs)
        lsum += sv[i];
    }
    #pragma unroll
    for (int m = 32; m >= 1; m >>= 1) lsum += __shfl_xor(lsum, m);
    if ((tid & 63) == 0) s_red[tid >> 6] = lsum;
    __syncthreads();
    float gsum = 0.0f;
    #pragma unroll
    for (int i = 0; i < 16; ++i) gsum += s_red[i];
    const float rinv = 1.0f / gsum;

    #pragma unroll
    for (int i = 0; i < 4; ++i) {
        orow[tid + i * NTHREADS] = sv[i] * rinv;
    }
}

extern "C" void kernel_launch(void* const* d_in, const int* in_sizes, int n_in,
                              void* d_out, int out_size, void* d_ws, size_t ws_size,
                              hipStream_t stream) {
    const float* q    = (const float*)d_in[0];
    const float* k    = (const float*)d_in[1];
    const int*   mask = (const int*)d_in[2];
    float*       out  = (float*)d_out;

    dim3 grid(Bdim * Hdim);
    dim3 block(NTHREADS);
    attn_cos_softmax<<<grid, block, 0, stream>>>(q, k, mask, out);
}